// Round 20
// baseline (303.117 us; speedup 1.0000x reference)
//
#include <hip/hip_runtime.h>
#include <cstdint>
#include <cstddef>

#define TT 4
#define BB 4
#define LL 1024
#define CC 256
#define HH 8
#define HD 32
#define NWIN 8
#define WIN 128
#define TOPKN 4
#define C3 768
#define PKW 24   // pk words per row: q[0..7], k[8..15], v[16..23]

// ---------------------------------------------------------------------------
// 1. region sums: c-split over 4 blocks
__global__ __launch_bounds__(64) void region_kernel(const float* __restrict__ x,
                                                    float* __restrict__ region) {
    int bn = blockIdx.x;          // b*NWIN + n
    int b = bn >> 3, n = bn & 7;
    int c = blockIdx.y * 64 + threadIdx.x;
    float tot = 0.0f;
    for (int r = 0; r < WIN; ++r) {
        int l = n * WIN + r;
        float s = 0.0f;
        for (int t = 0; t < TT; ++t) {
            s += x[(((size_t)t * BB + b) * LL + l) * CC + c];
        }
        tot += s;
    }
    region[(size_t)bn * CC + c] = tot;
}

// ---------------------------------------------------------------------------
// 2. routing
__global__ __launch_bounds__(64) void route_kernel(const float* __restrict__ region,
                                                   int* __restrict__ idx) {
    int b = blockIdx.x;
    __shared__ float reg[NWIN][CC];
    __shared__ float attn_r[NWIN][NWIN];
    int tid = threadIdx.x;
    for (int e = tid; e < NWIN * CC; e += 64)
        reg[e >> 8][e & 255] = region[(size_t)b * NWIN * CC + e];
    __syncthreads();
    int n = tid >> 3, m = tid & 7;
    float s = 0.0f;
    for (int c = 0; c < CC; ++c) s += reg[n][c] * reg[m][c];
    attn_r[n][m] = s * 0.0625f;   // C^-0.5 = 1/16 exact
    __syncthreads();
    if (tid < NWIN) {
        float vals[NWIN];
        for (int m2 = 0; m2 < NWIN; ++m2) vals[m2] = attn_r[tid][m2];
        for (int kk = 0; kk < TOPKN; ++kk) {
            int bi = 0; float bv = vals[0];
            for (int m2 = 1; m2 < NWIN; ++m2) {
                if (vals[m2] > bv) { bv = vals[m2]; bi = m2; }
            }
            idx[(b * NWIN + tid) * TOPKN + kk] = bi;
            vals[bi] = -INFINITY;
        }
    }
}

// ---------------------------------------------------------------------------
// 3a. fp32 GEMM + bias, 128x128 tile (qkv), conflict-free B reads.
__global__ __launch_bounds__(256, 3) void gemm_bias128(const float* __restrict__ A,
                                                       const float* __restrict__ W,
                                                       const float* __restrict__ bias,
                                                       float* __restrict__ C,
                                                       int M, int N, int K) {
    const int BM = 128, BN = 128, BK = 16, TM = 8;
    __shared__ float As[BK][BM + 4];
    __shared__ float Bs[BK][136];
    int tid = threadIdx.x;
    int tx = tid & 15, ty = tid >> 4;
    int bm = blockIdx.x * BM, bn = blockIdx.y * BN;
    float acc[TM][8] = {};
    for (int k0 = 0; k0 < K; k0 += BK) {
#pragma unroll
        for (int it = 0; it < 2; ++it) {
            int i = it * 256 + tid;
            int row = i >> 2, kc = (i & 3) * 4;
            float4 v = *(const float4*)(A + (size_t)(bm + row) * K + k0 + kc);
            As[kc + 0][row] = v.x; As[kc + 1][row] = v.y;
            As[kc + 2][row] = v.z; As[kc + 3][row] = v.w;
        }
#pragma unroll
        for (int it = 0; it < 2; ++it) {
            int i = it * 256 + tid;
            int kr = i >> 5, nc = (i & 31) * 4;
            float4 v = *(const float4*)(W + (size_t)(k0 + kr) * N + bn + nc);
            *(float4*)&Bs[kr][nc] = v;
        }
        __syncthreads();
#pragma unroll
        for (int kk = 0; kk < BK; ++kk) {
            float a[TM], bb[8];
            const float4* ap = (const float4*)&As[kk][ty * TM];
            float4 a0 = ap[0], a1 = ap[1];
            a[0]=a0.x; a[1]=a0.y; a[2]=a0.z; a[3]=a0.w;
            a[4]=a1.x; a[5]=a1.y; a[6]=a1.z; a[7]=a1.w;
            float4 b0 = *(const float4*)&Bs[kk][tx * 4];
            float4 b1 = *(const float4*)&Bs[kk][64 + tx * 4];
            bb[0]=b0.x; bb[1]=b0.y; bb[2]=b0.z; bb[3]=b0.w;
            bb[4]=b1.x; bb[5]=b1.y; bb[6]=b1.z; bb[7]=b1.w;
#pragma unroll
            for (int i = 0; i < TM; ++i)
#pragma unroll
                for (int j = 0; j < 8; ++j)
                    acc[i][j] = fmaf(a[i], bb[j], acc[i][j]);
        }
        __syncthreads();
    }
#pragma unroll
    for (int i = 0; i < TM; ++i) {
        int row = bm + ty * TM + i;
        int col0 = bn + tx * 4;
        int col1 = bn + 64 + tx * 4;
        float4 o0 = make_float4(acc[i][0] + bias[col0 + 0], acc[i][1] + bias[col0 + 1],
                                acc[i][2] + bias[col0 + 2], acc[i][3] + bias[col0 + 3]);
        float4 o1 = make_float4(acc[i][4] + bias[col1 + 0], acc[i][5] + bias[col1 + 1],
                                acc[i][6] + bias[col1 + 2], acc[i][7] + bias[col1 + 3]);
        *(float4*)&C[(size_t)row * N + col0] = o0;
        *(float4*)&C[(size_t)row * N + col1] = o1;
    }
}

// ---------------------------------------------------------------------------
// 3b. fp32 GEMM + bias, 64x64 tile (proj)
__global__ __launch_bounds__(256, 4) void gemm_bias64(const float* __restrict__ A,
                                                      const float* __restrict__ W,
                                                      const float* __restrict__ bias,
                                                      float* __restrict__ C,
                                                      int M, int N, int K) {
    const int BM = 64, BN = 64, BK = 16;
    __shared__ float As[BK][BM + 4];
    __shared__ float Bs[BK][72];
    int tid = threadIdx.x;
    int tx = tid & 15, ty = tid >> 4;
    int bm = blockIdx.x * BM, bn = blockIdx.y * BN;
    float acc[4][4] = {};
    for (int k0 = 0; k0 < K; k0 += BK) {
        {
            int row = tid >> 2, kc = (tid & 3) * 4;
            float4 v = *(const float4*)(A + (size_t)(bm + row) * K + k0 + kc);
            As[kc + 0][row] = v.x; As[kc + 1][row] = v.y;
            As[kc + 2][row] = v.z; As[kc + 3][row] = v.w;
        }
        {
            int kr = tid >> 4, nc = (tid & 15) * 4;
            float4 v = *(const float4*)(W + (size_t)(k0 + kr) * N + bn + nc);
            *(float4*)&Bs[kr][nc] = v;
        }
        __syncthreads();
#pragma unroll
        for (int kk = 0; kk < BK; ++kk) {
            float4 av = *(const float4*)&As[kk][ty * 4];
            float4 bv = *(const float4*)&Bs[kk][tx * 4];
            float a[4] = {av.x, av.y, av.z, av.w};
            float bb[4] = {bv.x, bv.y, bv.z, bv.w};
#pragma unroll
            for (int i = 0; i < 4; ++i)
#pragma unroll
                for (int j = 0; j < 4; ++j)
                    acc[i][j] = fmaf(a[i], bb[j], acc[i][j]);
        }
        __syncthreads();
    }
#pragma unroll
    for (int i = 0; i < 4; ++i) {
        int row = bm + ty * 4 + i;
        int col = bn + tx * 4;
        float4 o = make_float4(acc[i][0] + bias[col + 0], acc[i][1] + bias[col + 1],
                               acc[i][2] + bias[col + 2], acc[i][3] + bias[col + 3]);
        *(float4*)&C[(size_t)row * N + col] = o;
    }
}

// ---------------------------------------------------------------------------
// 4. LIF over T (final proj -> out)
__global__ __launch_bounds__(256) void lif_kernel(const float* src, float* dst, size_t stride) {
    size_t i = ((size_t)blockIdx.x * blockDim.x + threadIdx.x) * 4;
    float v[4] = {0.f, 0.f, 0.f, 0.f};
    for (int t = 0; t < TT; ++t) {
        float4 xv4 = *(const float4*)(src + (size_t)t * stride + i);
        float xv[4] = {xv4.x, xv4.y, xv4.z, xv4.w};
        float sp[4];
#pragma unroll
        for (int j = 0; j < 4; ++j) {
            v[j] = v[j] + (xv[j] - v[j]) * 0.5f;
            bool fire = (v[j] >= 1.0f);
            sp[j] = fire ? 1.0f : 0.0f;
            v[j] = fire ? 0.0f : v[j];
        }
        *(float4*)(dst + (size_t)t * stride + i) = make_float4(sp[0], sp[1], sp[2], sp[3]);
    }
}

// ---------------------------------------------------------------------------
// 4b. fused LIF + bit-pack over qkv: packs ALL of q/k/v as bits (24 words/row).
__global__ __launch_bounds__(192) void lif_pack_kernel(const float* __restrict__ qkv,
                                                       uint32_t* __restrict__ pk) {
    int row = blockIdx.x;            // b*LL + l
    int tid = threadIdx.x;
    int c = tid * 4;
    int wid = tid >> 6;              // wave 0..2 (c-range: wid*256 .. +255)
    int lane = tid & 63;
    const size_t stride = (size_t)BB * LL * C3;
    const float* base = qkv + (size_t)row * C3 + c;

    float v[4] = {0.f, 0.f, 0.f, 0.f};
    for (int t = 0; t < TT; ++t) {
        float4 xv4 = *(const float4*)(base + (size_t)t * stride);
        float xv[4] = {xv4.x, xv4.y, xv4.z, xv4.w};
        bool fire[4];
#pragma unroll
        for (int j = 0; j < 4; ++j) {
            v[j] = v[j] + (xv[j] - v[j]) * 0.5f;
            fire[j] = (v[j] >= 1.0f);
            v[j] = fire[j] ? 0.0f : v[j];
        }
        unsigned long long B0 = __ballot(fire[0]);
        unsigned long long B1 = __ballot(fire[1]);
        unsigned long long B2 = __ballot(fire[2]);
        unsigned long long B3 = __ballot(fire[3]);
        if (lane < 8) {
            uint32_t word = ((uint32_t)(B0 >> (8 * lane)) & 0xFFu)
                          | (((uint32_t)(B1 >> (8 * lane)) & 0xFFu) << 8)
                          | (((uint32_t)(B2 >> (8 * lane)) & 0xFFu) << 16)
                          | (((uint32_t)(B3 >> (8 * lane)) & 0xFFu) << 24);
            pk[((size_t)t * BB * LL + row) * PKW + wid * 8 + lane] = word;
        }
    }
}

// ---------------------------------------------------------------------------
// 5. fused sm+PV v20 — all-bits attention at v17 occupancy.
//    Block = (t,b,n,hp,h): 1024 blocks, 256 threads = (qg 0..63, dh 0..3).
//    Thread: 2 q x 8 d. V from bits (1 broadcast b128 per 4 k), extraction
//    8 bfe+cvt per k amortized over 2 q. No DMA, no k-loop barriers.
//    4 waves/SIMD. All fp chains identical to r17/r19 (verified absmax 0).
__global__ __launch_bounds__(256, 4) void attn_pv(const uint32_t* __restrict__ pk,
                                                  const int* __restrict__ idxws,
                                                  float* __restrict__ out) {
    int bid = blockIdx.x;
    int h = bid & 1, hp = (bid >> 1) & 3, n = (bid >> 3) & 7, b = (bid >> 6) & 3, t = bid >> 8;
    __shared__ float ptab[33][WIN];                   // 16.9 KB (col = q)
    __shared__ __align__(16) uint32_t kbs[512];       // 2 KB (this h)
    __shared__ __align__(16) uint32_t vbs[512];       // 2 KB (this h)
    int tid = threadIdx.x;
    int qg = tid & 63, dh = tid >> 6;
    int lbase = (t * BB + b) * LL;

    const int* ip = idxws + (b * NWIN + n) * TOPKN;
    int s0r = ip[0], s1r = ip[1], s2r = ip[2], s3r = ip[3];

    // stage gathered K and V bit-words (this h): 512 each, 2 per thread
#pragma unroll 2
    for (int e = tid; e < 512; e += 256) {
        int w = e >> 7;
        int sw = (w == 0) ? s0r : (w == 1) ? s1r : (w == 2) ? s2r : s3r;
        size_t rowb = (size_t)(lbase + sw * WIN + (e & 127)) * PKW + hp * 2 + h;
        kbs[e] = pk[rowb + 8];
        vbs[e] = pk[rowb + 16];
    }
    uint32_t qw0 = pk[(size_t)(lbase + n * WIN + qg) * PKW + hp * 2 + h];
    uint32_t qw1 = pk[(size_t)(lbase + n * WIN + qg + 64) * PKW + hp * 2 + h];
    __syncthreads();   // kbs/vbs visible

    // ---- fused softmax stats for q = tid (threads 0..127), r17 sequence
    const float ALPHA_SC = 0.17677669529663687f;   // hd^-0.5
    const uint4* kb4 = (const uint4*)kbs;
    if (tid < 128) {
        uint32_t qwt = (tid & 64) ? qw1 : qw0;     // q == tid
        int smax = 0;
#pragma unroll 8
        for (int k4 = 0; k4 < 128; ++k4) {
            uint4 w4 = kb4[k4];
            smax = max(smax, __popc(qwt & w4.x));
            smax = max(smax, __popc(qwt & w4.y));
            smax = max(smax, __popc(qwt & w4.z));
            smax = max(smax, __popc(qwt & w4.w));
        }
        float am = __fmul_rn((float)smax, ALPHA_SC);
        for (int s = 0; s <= 32; ++s)
            ptab[s][tid] = expf(__fsub_rn(__fmul_rn((float)s, ALPHA_SC), am));
        float Z = 0.0f;
#pragma unroll 4
        for (int k4 = 0; k4 < 128; ++k4) {
            uint4 w4 = kb4[k4];
            Z += ptab[__popc(qwt & w4.x)][tid];
            Z += ptab[__popc(qwt & w4.y)][tid];
            Z += ptab[__popc(qwt & w4.z)][tid];
            Z += ptab[__popc(qwt & w4.w)][tid];
        }
        for (int s = 0; s <= 32; ++s)
            ptab[s][tid] = ptab[s][tid] / Z;
    }
    __syncthreads();   // ptab final

    // ---- PV: 512 k ascending, no barriers. 2 q x 8 d per thread.
    const uint4* vb4 = (const uint4*)vbs;
    int po = 2 * dh;
    float acc0[8], acc1[8];
#pragma unroll
    for (int e = 0; e < 8; ++e) { acc0[e] = 0.0f; acc1[e] = 0.0f; }

#pragma unroll 2
    for (int g = 0; g < 128; ++g) {
        uint4 kw = kb4[g];
        uint4 vw = vb4[g];
#pragma unroll
        for (int r = 0; r < 4; ++r) {
            uint32_t krow = (r == 0) ? kw.x : (r == 1) ? kw.y : (r == 2) ? kw.z : kw.w;
            uint32_t vrow = (r == 0) ? vw.x : (r == 1) ? vw.y : (r == 2) ? vw.z : vw.w;
            uint32_t sh = vrow >> po;   // align this thread's dh slice
            float P0 = ptab[__popc(qw0 & krow)][qg];
            float P1 = ptab[__popc(qw1 & krow)][qg + 64];
#pragma unroll
            for (int e = 0; e < 8; ++e) {
                const int offs = (e & 3) * 8 + (e >> 2);  // bit of dim dh*8+e after >>po
                float vf = (float)((sh >> offs) & 1u);    // exactly 0.0f or 1.0f
                acc0[e] = fmaf(P0, vf, acc0[e]);
                acc1[e] = fmaf(P1, vf, acc1[e]);
            }
        }
    }

    size_t ob0 = (size_t)(lbase + n * WIN + qg) * CC + (hp * 2 + h) * 32 + dh * 8;
    size_t ob1 = ob0 + (size_t)64 * CC;
    *(float4*)&out[ob0]     = make_float4(acc0[0], acc0[1], acc0[2], acc0[3]);
    *(float4*)&out[ob0 + 4] = make_float4(acc0[4], acc0[5], acc0[6], acc0[7]);
    *(float4*)&out[ob1]     = make_float4(acc1[0], acc1[1], acc1[2], acc1[3]);
    *(float4*)&out[ob1 + 4] = make_float4(acc1[4], acc1[5], acc1[6], acc1[7]);
}

// ---------------------------------------------------------------------------
extern "C" void kernel_launch(void* const* d_in, const int* in_sizes, int n_in,
                              void* d_out, int out_size, void* d_ws, size_t ws_size,
                              hipStream_t stream) {
    const float* x      = (const float*)d_in[0];
    const float* w_qkv  = (const float*)d_in[1];
    const float* b_qkv  = (const float*)d_in[2];
    const float* w_proj = (const float*)d_in[3];
    const float* b_proj = (const float*)d_in[4];
    float* ws = (float*)d_ws;

    float* qkv      = ws;                 // 12582912 floats [T,B,L,3C] (pre-LIF values)
    float* attn_out = ws + 12582912;      // 4194304 floats [T,B,L,C]
    float* proj     = ws + 16777216;      // 4194304 floats [T,B,L,C]
    uint32_t* pkb   = (uint32_t*)proj;    // 393216 u32 (24/row): aliases proj (dead before gemm64)
    float* region   = ws + 20971520;      // 8192 floats
    int*   idxp     = (int*)(ws + 20979712);  // 128 ints
    float* outp     = (float*)d_out;

    region_kernel<<<dim3(BB * NWIN, 4), dim3(64), 0, stream>>>(x, region);
    route_kernel<<<dim3(BB), dim3(64), 0, stream>>>(region, idxp);
    gemm_bias128<<<dim3(128, 6), dim3(256), 0, stream>>>(x, w_qkv, b_qkv, qkv,
                                                         TT * BB * LL, C3, CC);
    lif_pack_kernel<<<dim3(BB * LL), dim3(192), 0, stream>>>(qkv, pkb);
    attn_pv<<<dim3(TT * BB * NWIN * 4 * 2), dim3(256), 0, stream>>>(pkb, idxp, attn_out);
    gemm_bias64<<<dim3(256, 4), dim3(256), 0, stream>>>(attn_out, w_proj, b_proj, proj,
                                                        TT * BB * LL, CC, CC);
    lif_kernel<<<dim3(1024), dim3(256), 0, stream>>>(proj, outp, (size_t)BB * LL * CC);
}

// Round 21
// 243.404 us; speedup vs baseline: 1.2453x; 1.2453x over previous
//
#include <hip/hip_runtime.h>
#include <cstdint>
#include <cstddef>

#define TT 4
#define BB 4
#define LL 1024
#define CC 256
#define HH 8
#define HD 32
#define NWIN 8
#define WIN 128
#define TOPKN 4
#define C3 768

// ---------------------------------------------------------------------------
// 1. region sums: c-split over 4 blocks
__global__ __launch_bounds__(64) void region_kernel(const float* __restrict__ x,
                                                    float* __restrict__ region) {
    int bn = blockIdx.x;          // b*NWIN + n
    int b = bn >> 3, n = bn & 7;
    int c = blockIdx.y * 64 + threadIdx.x;
    float tot = 0.0f;
    for (int r = 0; r < WIN; ++r) {
        int l = n * WIN + r;
        float s = 0.0f;
        for (int t = 0; t < TT; ++t) {
            s += x[(((size_t)t * BB + b) * LL + l) * CC + c];
        }
        tot += s;
    }
    region[(size_t)bn * CC + c] = tot;
}

// ---------------------------------------------------------------------------
// 2. routing
__global__ __launch_bounds__(64) void route_kernel(const float* __restrict__ region,
                                                   int* __restrict__ idx) {
    int b = blockIdx.x;
    __shared__ float reg[NWIN][CC];
    __shared__ float attn_r[NWIN][NWIN];
    int tid = threadIdx.x;
    for (int e = tid; e < NWIN * CC; e += 64)
        reg[e >> 8][e & 255] = region[(size_t)b * NWIN * CC + e];
    __syncthreads();
    int n = tid >> 3, m = tid & 7;
    float s = 0.0f;
    for (int c = 0; c < CC; ++c) s += reg[n][c] * reg[m][c];
    attn_r[n][m] = s * 0.0625f;   // C^-0.5 = 1/16 exact
    __syncthreads();
    if (tid < NWIN) {
        float vals[NWIN];
        for (int m2 = 0; m2 < NWIN; ++m2) vals[m2] = attn_r[tid][m2];
        for (int kk = 0; kk < TOPKN; ++kk) {
            int bi = 0; float bv = vals[0];
            for (int m2 = 1; m2 < NWIN; ++m2) {
                if (vals[m2] > bv) { bv = vals[m2]; bi = m2; }
            }
            idx[(b * NWIN + tid) * TOPKN + kk] = bi;
            vals[bi] = -INFINITY;
        }
    }
}

// ---------------------------------------------------------------------------
// 3a. fp32 GEMM + bias, 128x128 tile (qkv), conflict-free B reads.
__global__ __launch_bounds__(256, 3) void gemm_bias128(const float* __restrict__ A,
                                                       const float* __restrict__ W,
                                                       const float* __restrict__ bias,
                                                       float* __restrict__ C,
                                                       int M, int N, int K) {
    const int BM = 128, BN = 128, BK = 16, TM = 8;
    __shared__ float As[BK][BM + 4];
    __shared__ float Bs[BK][136];
    int tid = threadIdx.x;
    int tx = tid & 15, ty = tid >> 4;
    int bm = blockIdx.x * BM, bn = blockIdx.y * BN;
    float acc[TM][8] = {};
    for (int k0 = 0; k0 < K; k0 += BK) {
#pragma unroll
        for (int it = 0; it < 2; ++it) {
            int i = it * 256 + tid;
            int row = i >> 2, kc = (i & 3) * 4;
            float4 v = *(const float4*)(A + (size_t)(bm + row) * K + k0 + kc);
            As[kc + 0][row] = v.x; As[kc + 1][row] = v.y;
            As[kc + 2][row] = v.z; As[kc + 3][row] = v.w;
        }
#pragma unroll
        for (int it = 0; it < 2; ++it) {
            int i = it * 256 + tid;
            int kr = i >> 5, nc = (i & 31) * 4;
            float4 v = *(const float4*)(W + (size_t)(k0 + kr) * N + bn + nc);
            *(float4*)&Bs[kr][nc] = v;
        }
        __syncthreads();
#pragma unroll
        for (int kk = 0; kk < BK; ++kk) {
            float a[TM], bb[8];
            const float4* ap = (const float4*)&As[kk][ty * TM];
            float4 a0 = ap[0], a1 = ap[1];
            a[0]=a0.x; a[1]=a0.y; a[2]=a0.z; a[3]=a0.w;
            a[4]=a1.x; a[5]=a1.y; a[6]=a1.z; a[7]=a1.w;
            float4 b0 = *(const float4*)&Bs[kk][tx * 4];
            float4 b1 = *(const float4*)&Bs[kk][64 + tx * 4];
            bb[0]=b0.x; bb[1]=b0.y; bb[2]=b0.z; bb[3]=b0.w;
            bb[4]=b1.x; bb[5]=b1.y; bb[6]=b1.z; bb[7]=b1.w;
#pragma unroll
            for (int i = 0; i < TM; ++i)
#pragma unroll
                for (int j = 0; j < 8; ++j)
                    acc[i][j] = fmaf(a[i], bb[j], acc[i][j]);
        }
        __syncthreads();
    }
#pragma unroll
    for (int i = 0; i < TM; ++i) {
        int row = bm + ty * TM + i;
        int col0 = bn + tx * 4;
        int col1 = bn + 64 + tx * 4;
        float4 o0 = make_float4(acc[i][0] + bias[col0 + 0], acc[i][1] + bias[col0 + 1],
                                acc[i][2] + bias[col0 + 2], acc[i][3] + bias[col0 + 3]);
        float4 o1 = make_float4(acc[i][4] + bias[col1 + 0], acc[i][5] + bias[col1 + 1],
                                acc[i][6] + bias[col1 + 2], acc[i][7] + bias[col1 + 3]);
        *(float4*)&C[(size_t)row * N + col0] = o0;
        *(float4*)&C[(size_t)row * N + col1] = o1;
    }
}

// ---------------------------------------------------------------------------
// 3b. fp32 GEMM + bias, 64x64 tile (proj)
__global__ __launch_bounds__(256, 4) void gemm_bias64(const float* __restrict__ A,
                                                      const float* __restrict__ W,
                                                      const float* __restrict__ bias,
                                                      float* __restrict__ C,
                                                      int M, int N, int K) {
    const int BM = 64, BN = 64, BK = 16;
    __shared__ float As[BK][BM + 4];
    __shared__ float Bs[BK][72];
    int tid = threadIdx.x;
    int tx = tid & 15, ty = tid >> 4;
    int bm = blockIdx.x * BM, bn = blockIdx.y * BN;
    float acc[4][4] = {};
    for (int k0 = 0; k0 < K; k0 += BK) {
        {
            int row = tid >> 2, kc = (tid & 3) * 4;
            float4 v = *(const float4*)(A + (size_t)(bm + row) * K + k0 + kc);
            As[kc + 0][row] = v.x; As[kc + 1][row] = v.y;
            As[kc + 2][row] = v.z; As[kc + 3][row] = v.w;
        }
        {
            int kr = tid >> 4, nc = (tid & 15) * 4;
            float4 v = *(const float4*)(W + (size_t)(k0 + kr) * N + bn + nc);
            *(float4*)&Bs[kr][nc] = v;
        }
        __syncthreads();
#pragma unroll
        for (int kk = 0; kk < BK; ++kk) {
            float4 av = *(const float4*)&As[kk][ty * 4];
            float4 bv = *(const float4*)&Bs[kk][tx * 4];
            float a[4] = {av.x, av.y, av.z, av.w};
            float bb[4] = {bv.x, bv.y, bv.z, bv.w};
#pragma unroll
            for (int i = 0; i < 4; ++i)
#pragma unroll
                for (int j = 0; j < 4; ++j)
                    acc[i][j] = fmaf(a[i], bb[j], acc[i][j]);
        }
        __syncthreads();
    }
#pragma unroll
    for (int i = 0; i < 4; ++i) {
        int row = bm + ty * 4 + i;
        int col = bn + tx * 4;
        float4 o = make_float4(acc[i][0] + bias[col + 0], acc[i][1] + bias[col + 1],
                               acc[i][2] + bias[col + 2], acc[i][3] + bias[col + 3]);
        *(float4*)&C[(size_t)row * N + col] = o;
    }
}

// ---------------------------------------------------------------------------
// 4. LIF over T (final proj -> out)
__global__ __launch_bounds__(256) void lif_kernel(const float* src, float* dst, size_t stride) {
    size_t i = ((size_t)blockIdx.x * blockDim.x + threadIdx.x) * 4;
    float v[4] = {0.f, 0.f, 0.f, 0.f};
    for (int t = 0; t < TT; ++t) {
        float4 xv4 = *(const float4*)(src + (size_t)t * stride + i);
        float xv[4] = {xv4.x, xv4.y, xv4.z, xv4.w};
        float sp[4];
#pragma unroll
        for (int j = 0; j < 4; ++j) {
            v[j] = v[j] + (xv[j] - v[j]) * 0.5f;
            bool fire = (v[j] >= 1.0f);
            sp[j] = fire ? 1.0f : 0.0f;
            v[j] = fire ? 0.0f : v[j];
        }
        *(float4*)(dst + (size_t)t * stride + i) = make_float4(sp[0], sp[1], sp[2], sp[3]);
    }
}

// ---------------------------------------------------------------------------
// 4b. fused LIF + bit-pack (r17 version): q/k packed to bits, V third written
//     as spike floats (consumed by attn_pv DMA).
__global__ __launch_bounds__(192) void lif_pack_kernel(float* __restrict__ qkv,
                                                       uint32_t* __restrict__ pk) {
    int row = blockIdx.x;            // b*LL + l
    int tid = threadIdx.x;
    int c = tid * 4;
    int wid = tid >> 6;              // wave 0..2 (c-range: wid*256 .. +255)
    int lane = tid & 63;
    const size_t stride = (size_t)BB * LL * C3;
    float* base = qkv + (size_t)row * C3 + c;

    float v[4] = {0.f, 0.f, 0.f, 0.f};
    for (int t = 0; t < TT; ++t) {
        float4 xv4 = *(const float4*)(base + (size_t)t * stride);
        float xv[4] = {xv4.x, xv4.y, xv4.z, xv4.w};
        bool fire[4];
        float sp[4];
#pragma unroll
        for (int j = 0; j < 4; ++j) {
            v[j] = v[j] + (xv[j] - v[j]) * 0.5f;
            fire[j] = (v[j] >= 1.0f);
            sp[j] = fire[j] ? 1.0f : 0.0f;
            v[j] = fire[j] ? 0.0f : v[j];
        }
        if (c >= 512)   // V third: spikes consumed as floats by attn_pv
            *(float4*)(base + (size_t)t * stride) = make_float4(sp[0], sp[1], sp[2], sp[3]);
        unsigned long long B0 = __ballot(fire[0]);
        unsigned long long B1 = __ballot(fire[1]);
        unsigned long long B2 = __ballot(fire[2]);
        unsigned long long B3 = __ballot(fire[3]);
        if (lane < 8 && wid < 2) {
            uint32_t word = ((uint32_t)(B0 >> (8 * lane)) & 0xFFu)
                          | (((uint32_t)(B1 >> (8 * lane)) & 0xFFu) << 8)
                          | (((uint32_t)(B2 >> (8 * lane)) & 0xFFu) << 16)
                          | (((uint32_t)(B3 >> (8 * lane)) & 0xFFu) << 24);
            pk[((size_t)t * BB * LL + row) * 16 + wid * 8 + lane] = word;
        }
    }
}

// ---------------------------------------------------------------------------
// 5. fused sm+PV v21. Block = (t,b,n,hp,h): 1024 blocks, 128 threads =
//    (qg 0..31, dh 0..3). Thread: 4 q x 8 d (acc[4][8]) -> each broadcast V
//    b128 feeds 4x more FMA than v17 (1.4x less LDS/MAC). V float via
//    global_load_lds [2][64][32] dbuf, raw barriers + counted vmcnt(4).
//    Fused table-sm (r17 sequence; q = tid, qwt = qw[dh]). Bitwise exact.
__global__ __launch_bounds__(128, 2) void attn_pv(const float* __restrict__ spk,
                                                  const uint32_t* __restrict__ pk,
                                                  const int* __restrict__ idxws,
                                                  float* __restrict__ out) {
    int bid = blockIdx.x;
    int h = bid & 1, hp = (bid >> 1) & 3, n = (bid >> 3) & 7, b = (bid >> 6) & 3, t = bid >> 8;
    __shared__ __align__(16) float Vlds[2][64][32];   // 16 KB
    __shared__ float ptab[33][WIN];                   // 16.9 KB
    __shared__ __align__(16) uint32_t kbs[512];       // 2 KB (this h)
    int tid = threadIdx.x;                            // 128 threads
    int qg = tid & 31, dh = tid >> 5;                 // dh 0..3
    int lbase = (t * BB + b) * LL;

    const int* ip = idxws + (b * NWIN + n) * TOPKN;
    int s0r = ip[0], s1r = ip[1], s2r = ip[2], s3r = ip[3];

    // stage gathered K bit-words (this h): 512 words, 4 per thread
#pragma unroll 4
    for (int e = tid; e < 512; e += 128) {
        int w = e >> 7;
        int sw = (w == 0) ? s0r : (w == 1) ? s1r : (w == 2) ? s2r : s3r;
        kbs[e] = pk[(size_t)(lbase + sw * WIN + (e & 127)) * 16 + 8 + hp * 2 + h];
    }
    // 4 q-words per thread (q = qg + 32j)
    uint32_t qw[4];
#pragma unroll
    for (int j = 0; j < 4; ++j)
        qw[j] = pk[(size_t)(lbase + n * WIN + qg + 32 * j) * 16 + hp * 2 + h];

    // V DMA geometry: per-lane global src; LDS dest = wave-uniform + lane*16.
    // Thread covers rows (tid>>3)+16*it, cols (tid&7)*4 of each 64-row half.
    const float* vsrc = spk + (size_t)lbase * C3 + 512 + hp * 64 + h * 32
                        + (size_t)(tid >> 3) * C3 + (tid & 7) * 4;
    int wvoff = (tid >> 6) * 1024;   // wave id * 1 KB (wave-uniform)

#define STAGE_HALF(hw_)                                                              \
    do {                                                                             \
        int hw = (hw_);                                                              \
        int ww = hw >> 1;                                                            \
        int sw = (ww == 0) ? s0r : (ww == 1) ? s1r : (ww == 2) ? s2r : s3r;          \
        const float* src = vsrc + (size_t)(sw * WIN + (hw & 1) * 64) * C3;           \
        char* lb = (char*)(&Vlds[hw & 1][0][0]) + wvoff;                             \
        _Pragma("unroll")                                                            \
        for (int it = 0; it < 4; ++it) {                                             \
            __builtin_amdgcn_global_load_lds(                                        \
                (const __attribute__((address_space(1))) void*)(src + (size_t)it * 16 * C3), \
                (__attribute__((address_space(3))) void*)(lb + it * 2048), 16, 0, 0);\
        }                                                                            \
    } while (0)

    STAGE_HALF(0);
    STAGE_HALF(1);

    // kbs visible to all (raw barrier: DMA keeps flying)
    asm volatile("s_waitcnt lgkmcnt(0)" ::: "memory");
    __builtin_amdgcn_s_barrier();

    // ---- fused softmax stats for q = tid (all 128 threads), r17 sequence
    const float ALPHA_SC = 0.17677669529663687f;   // hd^-0.5
    const uint4* kb4 = (const uint4*)kbs;
    {
        uint32_t qwt = qw[dh];                     // q == qg + 32*dh == tid
        int smax = 0;
#pragma unroll 8
        for (int k4 = 0; k4 < 128; ++k4) {
            uint4 w4 = kb4[k4];
            smax = max(smax, __popc(qwt & w4.x));
            smax = max(smax, __popc(qwt & w4.y));
            smax = max(smax, __popc(qwt & w4.z));
            smax = max(smax, __popc(qwt & w4.w));
        }
        float am = __fmul_rn((float)smax, ALPHA_SC);
        for (int s = 0; s <= 32; ++s)
            ptab[s][tid] = expf(__fsub_rn(__fmul_rn((float)s, ALPHA_SC), am));
        float Z = 0.0f;
#pragma unroll 4
        for (int k4 = 0; k4 < 128; ++k4) {
            uint4 w4 = kb4[k4];
            Z += ptab[__popc(qwt & w4.x)][tid];
            Z += ptab[__popc(qwt & w4.y)][tid];
            Z += ptab[__popc(qwt & w4.z)][tid];
            Z += ptab[__popc(qwt & w4.w)][tid];
        }
        for (int s = 0; s <= 32; ++s)
            ptab[s][tid] = ptab[s][tid] / Z;
    }

    float acc[4][8];
#pragma unroll
    for (int j = 0; j < 4; ++j)
#pragma unroll
        for (int e = 0; e < 8; ++e) acc[j][e] = 0.0f;

    // ptab drained; half0 DMA complete (half1's 4 in flight)
    asm volatile("s_waitcnt lgkmcnt(0)" ::: "memory");
    asm volatile("s_waitcnt vmcnt(4)" ::: "memory");
    __builtin_amdgcn_s_barrier();

#pragma unroll 1
    for (int hw = 0; hw < 8; ++hw) {
        const uint4* kw4 = kb4 + hw * 16;
        const float* vb = &Vlds[hw & 1][0][dh * 8];
#pragma unroll 2
        for (int g = 0; g < 16; ++g) {
            uint4 kw = kw4[g];
            const float* pr = vb + g * 128;   // 4 rows of 32 floats
#pragma unroll
            for (int r = 0; r < 4; ++r) {
                uint32_t krow = (r == 0) ? kw.x : (r == 1) ? kw.y
                              : (r == 2) ? kw.z : kw.w;
                float P0 = ptab[__popc(qw[0] & krow)][qg];
                float P1 = ptab[__popc(qw[1] & krow)][qg + 32];
                float P2 = ptab[__popc(qw[2] & krow)][qg + 64];
                float P3 = ptab[__popc(qw[3] & krow)][qg + 96];
                const float4* vp = (const float4*)(pr + r * 32);
                float4 v0 = vp[0], v1 = vp[1];
                float vv[8] = {v0.x, v0.y, v0.z, v0.w, v1.x, v1.y, v1.z, v1.w};
#pragma unroll
                for (int e = 0; e < 8; ++e) {
                    acc[0][e] = fmaf(P0, vv[e], acc[0][e]);
                    acc[1][e] = fmaf(P1, vv[e], acc[1][e]);
                    acc[2][e] = fmaf(P2, vv[e], acc[2][e]);
                    acc[3][e] = fmaf(P3, vv[e], acc[3][e]);
                }
            }
        }

        if (hw < 7) {
            __builtin_amdgcn_s_barrier();     // all waves done reading buf[hw&1]
            if (hw < 6) {
                STAGE_HALF(hw + 2);           // refill buf[hw&1] (async)
                asm volatile("s_waitcnt vmcnt(4)" ::: "memory");  // S(hw+1) done
            } else {
                asm volatile("s_waitcnt vmcnt(0)" ::: "memory");  // S(7) done
            }
            __builtin_amdgcn_s_barrier();     // half hw+1 visible to all waves
        }
    }
#undef STAGE_HALF

#pragma unroll
    for (int j = 0; j < 4; ++j) {
        size_t ob = (size_t)(lbase + n * WIN + qg + 32 * j) * CC
                    + (hp * 2 + h) * 32 + dh * 8;
        *(float4*)&out[ob]     = make_float4(acc[j][0], acc[j][1], acc[j][2], acc[j][3]);
        *(float4*)&out[ob + 4] = make_float4(acc[j][4], acc[j][5], acc[j][6], acc[j][7]);
    }
}

// ---------------------------------------------------------------------------
extern "C" void kernel_launch(void* const* d_in, const int* in_sizes, int n_in,
                              void* d_out, int out_size, void* d_ws, size_t ws_size,
                              hipStream_t stream) {
    const float* x      = (const float*)d_in[0];
    const float* w_qkv  = (const float*)d_in[1];
    const float* b_qkv  = (const float*)d_in[2];
    const float* w_proj = (const float*)d_in[3];
    const float* b_proj = (const float*)d_in[4];
    float* ws = (float*)d_ws;

    float* qkv      = ws;                 // 12582912 floats [T,B,L,3C] (V-third = spikes)
    float* attn_out = ws + 12582912;      // 4194304 floats [T,B,L,C]
    float* proj     = ws + 16777216;      // 4194304 floats [T,B,L,C]
    uint32_t* pkb   = (uint32_t*)proj;    // 262144 u32: aliases proj (dead before gemm64)
    float* region   = ws + 20971520;      // 8192 floats
    int*   idxp     = (int*)(ws + 20979712);  // 128 ints
    float* outp     = (float*)d_out;

    region_kernel<<<dim3(BB * NWIN, 4), dim3(64), 0, stream>>>(x, region);
    route_kernel<<<dim3(BB), dim3(64), 0, stream>>>(region, idxp);
    gemm_bias128<<<dim3(128, 6), dim3(256), 0, stream>>>(x, w_qkv, b_qkv, qkv,
                                                         TT * BB * LL, C3, CC);
    lif_pack_kernel<<<dim3(BB * LL), dim3(192), 0, stream>>>(qkv, pkb);
    attn_pv<<<dim3(TT * BB * NWIN * 4 * 2), dim3(128), 0, stream>>>(qkv, pkb, idxp, attn_out);
    gemm_bias64<<<dim3(256, 4), dim3(256), 0, stream>>>(attn_out, w_proj, b_proj, proj,
                                                        TT * BB * LL, CC, CC);
    lif_kernel<<<dim3(1024), dim3(256), 0, stream>>>(proj, outp, (size_t)BB * LL * CC);
}